// Round 3
// baseline (584.228 us; speedup 1.0000x reference)
//
#include <hip/hip_runtime.h>

// ITA Self-Attention QAT — round 3 (full split precision)
// B=8, N=1024, E=768, P=768, H=12, D=64
//
// vs round 2 (absmax 0.0225): P/V/ctx were single bf16 -> now ALL links split
// hi/lo bf16 (~17-bit mantissa). Quant rounding done in f64 (matches f64 np
// reference at half-integer boundaries). Remaining error: f32 MFMA accum
// (~1e-6 rel) + dropped lo*lo terms (~2^-18 rel).

typedef unsigned short u16;
typedef __attribute__((ext_vector_type(8))) short short8;
typedef __attribute__((ext_vector_type(4))) float f32x4;

#define LOG2E_F 1.4426950408889634f

__device__ __forceinline__ f32x4 mfma_bf(short8 a, short8 b, f32x4 c) {
  return __builtin_amdgcn_mfma_f32_16x16x32_bf16(a, b, c, 0, 0, 0);
}
// round-to-nearest-even f32 -> bf16 bits
__device__ __forceinline__ u16 f2b(float f) {
  union { float f; unsigned u; } v; v.f = f;
  unsigned u = v.u + 0x7FFF + ((v.u >> 16) & 1);
  return (u16)(u >> 16);
}
__device__ __forceinline__ float b2f(u16 b) {
  union { unsigned u; float f; } v; v.u = ((unsigned)b) << 16;
  return v.f;
}
__device__ __forceinline__ void splitf(float v, u16& hi, u16& lo) {
  hi = f2b(v);
  lo = f2b(v - b2f(hi));
}
__device__ __forceinline__ void gload16(const void* g, void* l) {
  __builtin_amdgcn_global_load_lds(
      (const __attribute__((address_space(1))) void*)g,
      (__attribute__((address_space(3))) void*)l, 16, 0, 0);
}

// ---------------- amax reduction ----------------
__global__ __launch_bounds__(256) void amax_part_kernel(
    const float4* __restrict__ x, float* __restrict__ part, int n4) {
  float m = 0.f;
  int i = blockIdx.x * 256 + threadIdx.x;
  const int stride = gridDim.x * 256;
  for (; i < n4; i += stride) {
    float4 v = x[i];
    m = fmaxf(m, fmaxf(fmaxf(fabsf(v.x), fabsf(v.y)),
                       fmaxf(fabsf(v.z), fabsf(v.w))));
  }
  #pragma unroll
  for (int o = 1; o < 64; o <<= 1) m = fmaxf(m, __shfl_xor(m, o));
  __shared__ float sw[4];
  if ((threadIdx.x & 63) == 0) sw[threadIdx.x >> 6] = m;
  __syncthreads();
  if (threadIdx.x == 0)
    part[blockIdx.x] = fmaxf(fmaxf(sw[0], sw[1]), fmaxf(sw[2], sw[3]));
}

__global__ __launch_bounds__(256) void amax_fin_kernel(
    const float* __restrict__ part, double* __restrict__ dsc) {
  const int t = threadIdx.x;
  float m = fmaxf(fmaxf(part[t], part[t + 256]),
                  fmaxf(part[t + 512], part[t + 768]));
  #pragma unroll
  for (int o = 1; o < 64; o <<= 1) m = fmaxf(m, __shfl_xor(m, o));
  __shared__ float sw[4];
  if ((t & 63) == 0) sw[t >> 6] = m;
  __syncthreads();
  if (t == 0) {
    double sd = (double)(fmaxf(fmaxf(sw[0], sw[1]), fmaxf(sw[2], sw[3]))) / 127.0;
    if (sd < 1e-8) sd = 1e-8;
    dsc[0] = sd;
    dsc[1] = 1.0 / sd;
  }
}

// ---------------- quantize (f64 rounding): n = clip(rint(x/s)) exact bf16 ----
__global__ __launch_bounds__(256) void quant_kernel(
    const float4* __restrict__ x, u16* __restrict__ xq,
    const double* __restrict__ dsc, int n4) {
  const double rinv = dsc[1];
  int i = blockIdx.x * 256 + threadIdx.x;
  const int stride = gridDim.x * 256;
  for (; i < n4; i += stride) {
    float4 v = x[i];
    ushort4 u;
    u.x = f2b((float)fmin(fmax(rint((double)v.x * rinv), -128.0), 127.0));
    u.y = f2b((float)fmin(fmax(rint((double)v.y * rinv), -128.0), 127.0));
    u.z = f2b((float)fmin(fmax(rint((double)v.z * rinv), -128.0), 127.0));
    u.w = f2b((float)fmin(fmax(rint((double)v.w * rinv), -128.0), 127.0));
    *(ushort4*)&xq[(size_t)i * 4] = u;
  }
}

// ---------------- weight prep: transpose + hi/lo split (scale folded) -------
__global__ __launch_bounds__(256) void prep_weights_kernel(
    const float* __restrict__ Wq, const float* __restrict__ Wk,
    const float* __restrict__ Wv, const float* __restrict__ Wo,
    const double* __restrict__ dsc,
    u16* __restrict__ Wqh, u16* __restrict__ Wql,
    u16* __restrict__ Wkh, u16* __restrict__ Wkl,
    u16* __restrict__ Wvh, u16* __restrict__ Wvl,
    u16* __restrict__ Woh, u16* __restrict__ Wol) {
  const double sd = dsc[0];
  int idx = blockIdx.x * 256 + threadIdx.x;
  if (idx >= 768 * 768) return;
  const int r = idx / 768, c = idx - r * 768;
  const size_t src = (size_t)c * 768 + r;
  u16 hi, lo;
  splitf((float)(sd * (double)Wq[src]), hi, lo); Wqh[idx] = hi; Wql[idx] = lo;
  splitf((float)(sd * (double)Wk[src]), hi, lo); Wkh[idx] = hi; Wkl[idx] = lo;
  splitf((float)(sd * (double)Wv[src]), hi, lo); Wvh[idx] = hi; Wvl[idx] = lo;
  splitf(Wo[src], hi, lo);                       Woh[idx] = hi; Wol[idx] = lo;
}

// ------- projection GEMM: C[m,n] = sum_k A[m,k]*(B0+B1)[n,k] + bias[n] ------
// A exact bf16 ints; B split. Output SPLIT hi/lo bf16.
// MODE 0: layout [B,H,N,D] (Q, K);  MODE 1: layout [B,H,D,N] (V transposed)
template <int MODE>
__global__ __launch_bounds__(256) void gemm_bt(
    const u16* __restrict__ A, const u16* __restrict__ B0,
    const u16* __restrict__ B1, const float* __restrict__ bias,
    u16* __restrict__ C0, u16* __restrict__ C1, int K) {
  __shared__ u16 As[128 * 32];
  __shared__ u16 Bs0[128 * 32];
  __shared__ u16 Bs1[128 * 32];
  const int tid = threadIdx.x;
  const int w = tid >> 6, l = tid & 63;
  const int l15 = l & 15, lk = l >> 4;
  const int wr = w >> 1, wc = w & 1;
  const int tn = blockIdx.x, tm = blockIdx.y;
  f32x4 acc[4][4] = {};
  const int rA = tid >> 2;
  const int c8 = (tid & 3) * 8;
  const int nk = K >> 5;
  for (int kt = 0; kt < nk; ++kt) {
    __syncthreads();
    {
      const int k0 = kt * 32 + c8;
      const u16* gA0 = A + (size_t)(tm * 128 + rA) * K + k0;
      const u16* gB0a = B0 + (size_t)(tn * 128 + rA) * K + k0;
      const u16* gB1a = B1 + (size_t)(tn * 128 + rA) * K + k0;
      char* lA  = (char*)As  + w * 1024;
      char* lB0 = (char*)Bs0 + w * 1024;
      char* lB1 = (char*)Bs1 + w * 1024;
      gload16(gA0, lA);
      gload16(gA0 + (size_t)64 * K, lA + 4096);
      gload16(gB0a, lB0);
      gload16(gB0a + (size_t)64 * K, lB0 + 4096);
      gload16(gB1a, lB1);
      gload16(gB1a + (size_t)64 * K, lB1 + 4096);
    }
    __syncthreads();
    short8 af[4], b0f[4], b1f[4];
    #pragma unroll
    for (int mi = 0; mi < 4; ++mi)
      af[mi] = *(const short8*)&As[(wr * 64 + mi * 16 + l15) * 32 + lk * 8];
    #pragma unroll
    for (int ni = 0; ni < 4; ++ni) {
      b0f[ni] = *(const short8*)&Bs0[(wc * 64 + ni * 16 + l15) * 32 + lk * 8];
      b1f[ni] = *(const short8*)&Bs1[(wc * 64 + ni * 16 + l15) * 32 + lk * 8];
    }
    #pragma unroll
    for (int mi = 0; mi < 4; ++mi)
      #pragma unroll
      for (int ni = 0; ni < 4; ++ni) {
        acc[mi][ni] = mfma_bf(af[mi], b0f[ni], acc[mi][ni]);
        acc[mi][ni] = mfma_bf(af[mi], b1f[ni], acc[mi][ni]);
      }
  }
  #pragma unroll
  for (int mi = 0; mi < 4; ++mi) {
    #pragma unroll
    for (int ni = 0; ni < 4; ++ni) {
      #pragma unroll
      for (int j = 0; j < 4; ++j) {
        const int gm = tm * 128 + wr * 64 + mi * 16 + lk * 4 + j;
        const int gc = tn * 128 + wc * 64 + ni * 16 + l15;
        float v = acc[mi][ni][j] + bias[gc];
        const int b = gm >> 10, n = gm & 1023, h = gc >> 6, d = gc & 63;
        u16 hi, lo; splitf(v, hi, lo);
        size_t o;
        if (MODE == 0) o = (((size_t)b * 12 + h) * 1024 + n) * 64 + d;
        else           o = (((size_t)b * 12 + h) * 64 + d) * 1024 + n;
        C0[o] = hi;
        C1[o] = lo;
      }
    }
  }
}

// ------- final GEMM: out = (A0+A1) @ (B0+B1)^T + bias, fp32 out -------------
__global__ __launch_bounds__(256) void gemm_final(
    const u16* __restrict__ A0, const u16* __restrict__ A1,
    const u16* __restrict__ B0, const u16* __restrict__ B1,
    const float* __restrict__ bias, float* __restrict__ C, int K) {
  __shared__ u16 As0[128 * 32];
  __shared__ u16 As1[128 * 32];
  __shared__ u16 Bs0[128 * 32];
  __shared__ u16 Bs1[128 * 32];
  const int tid = threadIdx.x;
  const int w = tid >> 6, l = tid & 63;
  const int l15 = l & 15, lk = l >> 4;
  const int wr = w >> 1, wc = w & 1;
  const int tn = blockIdx.x, tm = blockIdx.y;
  f32x4 acc[4][4] = {};
  const int rA = tid >> 2;
  const int c8 = (tid & 3) * 8;
  const int nk = K >> 5;
  for (int kt = 0; kt < nk; ++kt) {
    __syncthreads();
    {
      const int k0 = kt * 32 + c8;
      const u16* gA0 = A0 + (size_t)(tm * 128 + rA) * K + k0;
      const u16* gA1 = A1 + (size_t)(tm * 128 + rA) * K + k0;
      const u16* gB0a = B0 + (size_t)(tn * 128 + rA) * K + k0;
      const u16* gB1a = B1 + (size_t)(tn * 128 + rA) * K + k0;
      char* lA0 = (char*)As0 + w * 1024;
      char* lA1 = (char*)As1 + w * 1024;
      char* lB0 = (char*)Bs0 + w * 1024;
      char* lB1 = (char*)Bs1 + w * 1024;
      gload16(gA0, lA0);
      gload16(gA0 + (size_t)64 * K, lA0 + 4096);
      gload16(gA1, lA1);
      gload16(gA1 + (size_t)64 * K, lA1 + 4096);
      gload16(gB0a, lB0);
      gload16(gB0a + (size_t)64 * K, lB0 + 4096);
      gload16(gB1a, lB1);
      gload16(gB1a + (size_t)64 * K, lB1 + 4096);
    }
    __syncthreads();
    short8 a0f[4], a1f[4], b0f[4], b1f[4];
    #pragma unroll
    for (int mi = 0; mi < 4; ++mi) {
      a0f[mi] = *(const short8*)&As0[(wr * 64 + mi * 16 + l15) * 32 + lk * 8];
      a1f[mi] = *(const short8*)&As1[(wr * 64 + mi * 16 + l15) * 32 + lk * 8];
    }
    #pragma unroll
    for (int ni = 0; ni < 4; ++ni) {
      b0f[ni] = *(const short8*)&Bs0[(wc * 64 + ni * 16 + l15) * 32 + lk * 8];
      b1f[ni] = *(const short8*)&Bs1[(wc * 64 + ni * 16 + l15) * 32 + lk * 8];
    }
    #pragma unroll
    for (int mi = 0; mi < 4; ++mi)
      #pragma unroll
      for (int ni = 0; ni < 4; ++ni) {
        acc[mi][ni] = mfma_bf(a0f[mi], b0f[ni], acc[mi][ni]);
        acc[mi][ni] = mfma_bf(a0f[mi], b1f[ni], acc[mi][ni]);
        acc[mi][ni] = mfma_bf(a1f[mi], b0f[ni], acc[mi][ni]);
      }
  }
  #pragma unroll
  for (int mi = 0; mi < 4; ++mi)
    #pragma unroll
    for (int ni = 0; ni < 4; ++ni)
      #pragma unroll
      for (int j = 0; j < 4; ++j) {
        const int gm = tm * 128 + wr * 64 + mi * 16 + lk * 4 + j;
        const int gc = tn * 128 + wc * 64 + ni * 16 + l15;
        C[(size_t)gm * 768 + gc] = acc[mi][ni][j] + bias[gc];
      }
}

// ---------------- fused attention ----------------
// grid: (32 q-tiles, 96 bh). 512 threads = 8 waves.
__global__ __launch_bounds__(512) void attn_kernel(
    const u16* __restrict__ Qh, const u16* __restrict__ Ql,
    const u16* __restrict__ Kh, const u16* __restrict__ Kl,
    const u16* __restrict__ Vth, const u16* __restrict__ Vtl,
    u16* __restrict__ ctxh, u16* __restrict__ ctxl) {
  __shared__ float sm[32 * 1032];   // logits fp32; later: Ph|Pl u16 planes
  __shared__ float rowsum[32];
  const int qt = blockIdx.x, bh = blockIdx.y;
  const int b = bh / 12, h = bh - b * 12;
  const int tid = threadIdx.x;
  const int w = tid >> 6, l = tid & 63;
  const int l15 = l & 15, lk = l >> 4;
  const int rb = w & 1, grp = w >> 1;

  // ---- pass 1: logits = (Qh+Ql)(Kh+Kl)^T, drop Ql*Kl ----
  {
    const size_t qoff = ((size_t)bh * 1024 + qt * 32 + rb * 16 + l15) * 64 + lk * 8;
    short8 qh0 = *(const short8*)(Qh + qoff);
    short8 qh1 = *(const short8*)(Qh + qoff + 32);
    short8 ql0 = *(const short8*)(Ql + qoff);
    short8 ql1 = *(const short8*)(Ql + qoff + 32);
    const u16* kbh = Kh + (size_t)bh * 1024 * 64 + lk * 8;
    const u16* kbl = Kl + (size_t)bh * 1024 * 64 + lk * 8;
    #pragma unroll 4
    for (int cb = grp * 16; cb < grp * 16 + 16; ++cb) {
      const size_t koff = (size_t)(cb * 16 + l15) * 64;
      short8 kh0 = *(const short8*)(kbh + koff);
      short8 kh1 = *(const short8*)(kbh + koff + 32);
      short8 kl0 = *(const short8*)(kbl + koff);
      short8 kl1 = *(const short8*)(kbl + koff + 32);
      f32x4 acc = {0.f, 0.f, 0.f, 0.f};
      acc = mfma_bf(qh0, kh0, acc);
      acc = mfma_bf(qh1, kh1, acc);
      acc = mfma_bf(qh0, kl0, acc);
      acc = mfma_bf(qh1, kl1, acc);
      acc = mfma_bf(ql0, kh0, acc);
      acc = mfma_bf(ql1, kh1, acc);
      float* dst = &sm[(rb * 16 + lk * 4) * 1032 + cb * 16 + l15];
      #pragma unroll
      for (int j = 0; j < 4; ++j) dst[j * 1032] = acc[j];
    }
  }
  __syncthreads();

  // ---- softmax (ITA integer-approx, exact one-pass), P split hi/lo ----
  float pv[64];
  {
    const int row = tid >> 4, ii = tid & 15;
    const float* src = &sm[row * 1032 + ii];
    float m = -3.0e38f;
    #pragma unroll
    for (int j = 0; j < 64; ++j) {
      float z = src[j * 16] * LOG2E_F;
      pv[j] = z;
      m = fmaxf(m, z);
    }
    #pragma unroll
    for (int o = 1; o < 16; o <<= 1) m = fmaxf(m, __shfl_xor(m, o));
    float s = 0.f;
    #pragma unroll
    for (int j = 0; j < 64; ++j) {
      float zz = pv[j] - m;
      float zi = floorf(zz);
      float zf = zz - zi;
      float p = ldexpf(1.0f + zf, (int)zi);  // exact 2^zi*(1+zf)
      pv[j] = p;
      s += p;
    }
    #pragma unroll
    for (int o = 1; o < 16; o <<= 1) s += __shfl_xor(s, o);
    if (ii == 0) rowsum[row] = s;
    __syncthreads();  // all logits reads done before aliasing writes
    u16* Ph = (u16*)sm;          // [32][1032] u16
    u16* Pl = Ph + 32 * 1032;    // second plane; total = 32*1032*4 bytes exactly
    #pragma unroll
    for (int j = 0; j < 64; ++j) {
      u16 hi, lo; splitf(pv[j], hi, lo);
      Ph[row * 1032 + ii + j * 16] = hi;
      Pl[row * 1032 + ii + j * 16] = lo;
    }
  }
  __syncthreads();

  // ---- pass 2: ctx = ((Ph+Pl) @ (Vh+Vl)) / rowsum, drop Pl*Vl ----
  {
    const u16* Ph = (const u16*)sm;
    const u16* Pl = Ph + 32 * 1032;
    const size_t voff = ((size_t)bh * 64 + grp * 16 + l15) * 1024 + lk * 8;
    const u16* vh = Vth + voff;
    const u16* vl = Vtl + voff;
    const int poff = (rb * 16 + l15) * 1032 + lk * 8;
    f32x4 acc = {0.f, 0.f, 0.f, 0.f};
    #pragma unroll 4
    for (int mt = 0; mt < 32; ++mt) {
      short8 ph = *(const short8*)(Ph + poff + mt * 32);
      short8 pl = *(const short8*)(Pl + poff + mt * 32);
      short8 bh0 = *(const short8*)(vh + mt * 32);
      short8 bl0 = *(const short8*)(vl + mt * 32);
      acc = mfma_bf(ph, bh0, acc);
      acc = mfma_bf(ph, bl0, acc);
      acc = mfma_bf(pl, bh0, acc);
    }
    const int n0 = qt * 32 + rb * 16 + lk * 4;
    const int col = h * 64 + grp * 16 + l15;
    #pragma unroll
    for (int j = 0; j < 4; ++j) {
      float v = acc[j] / rowsum[rb * 16 + lk * 4 + j];
      u16 hi, lo; splitf(v, hi, lo);
      const size_t o = ((size_t)b * 1024 + n0 + j) * 768 + col;
      ctxh[o] = hi;
      ctxl[o] = lo;
    }
  }
}

// ---------------- host ----------------
extern "C" void kernel_launch(void* const* d_in, const int* in_sizes, int n_in,
                              void* d_out, int out_size, void* d_ws, size_t ws_size,
                              hipStream_t stream) {
  const float* x  = (const float*)d_in[0];
  const float* Wq = (const float*)d_in[1];
  const float* bq = (const float*)d_in[2];
  const float* Wk = (const float*)d_in[3];
  const float* bk = (const float*)d_in[4];
  const float* Wv = (const float*)d_in[5];
  const float* bv = (const float*)d_in[6];
  const float* Wo = (const float*)d_in[7];
  const float* bo = (const float*)d_in[8];
  float* out = (float*)d_out;

  char* ws = (char*)d_ws;
  float* part   = (float*)ws;                // 1024 floats
  double* dsc   = (double*)(ws + 4096);      // {scale, 1/scale}
  size_t off = 8192;
  const size_t WB = (size_t)768 * 768;
  const size_t XB = (size_t)8192 * 768;
  u16* xq  = (u16*)(ws + off); off += XB * 2;
  u16* Wqh = (u16*)(ws + off); off += WB * 2;
  u16* Wql = (u16*)(ws + off); off += WB * 2;
  u16* Wkh = (u16*)(ws + off); off += WB * 2;
  u16* Wkl = (u16*)(ws + off); off += WB * 2;
  u16* Wvh = (u16*)(ws + off); off += WB * 2;
  u16* Wvl = (u16*)(ws + off); off += WB * 2;
  u16* Woh = (u16*)(ws + off); off += WB * 2;
  u16* Wol = (u16*)(ws + off); off += WB * 2;
  u16* Qhb = (u16*)(ws + off); off += XB * 2;
  u16* Qlb = (u16*)(ws + off); off += XB * 2;
  u16* Khb = (u16*)(ws + off); off += XB * 2;
  u16* Klb = (u16*)(ws + off); off += XB * 2;
  u16* Vth = (u16*)(ws + off); off += XB * 2;
  u16* Vtl = (u16*)(ws + off); off += XB * 2;
  u16* ctxl = (u16*)(ws + off); off += XB * 2;
  u16* ctxh = xq;  // xq dead after V GEMM; attn (writer) runs after -> safe
  (void)ws_size; (void)in_sizes; (void)n_in; (void)out_size;

  const int n4 = (8 * 1024 * 768) / 4;
  amax_part_kernel<<<1024, 256, 0, stream>>>((const float4*)x, part, n4);
  amax_fin_kernel<<<1, 256, 0, stream>>>(part, dsc);
  quant_kernel<<<2048, 256, 0, stream>>>((const float4*)x, xq, dsc, n4);
  prep_weights_kernel<<<(768 * 768 + 255) / 256, 256, 0, stream>>>(
      Wq, Wk, Wv, Wo, dsc, Wqh, Wql, Wkh, Wkl, Wvh, Wvl, Woh, Wol);

  dim3 gg(6, 64);
  gemm_bt<0><<<gg, 256, 0, stream>>>(xq, Wqh, Wql, bq, Qhb, Qlb, 768);
  gemm_bt<0><<<gg, 256, 0, stream>>>(xq, Wkh, Wkl, bk, Khb, Klb, 768);
  gemm_bt<1><<<gg, 256, 0, stream>>>(xq, Wvh, Wvl, bv, Vth, Vtl, 768);
  attn_kernel<<<dim3(32, 96), 512, 0, stream>>>(Qhb, Qlb, Khb, Klb, Vth, Vtl,
                                                ctxh, ctxl);
  gemm_final<<<gg, 256, 0, stream>>>(ctxh, ctxl, Woh, Wol, bo, out, 768);
}

// Round 4
// 202.593 us; speedup vs baseline: 2.8838x; 2.8838x over previous
//
#include <hip/hip_runtime.h>

// ITA Self-Attention QAT — round 4 (f16 single-plane + flash 2-pass attention)
// B=8, N=1024, E=768, P=768, H=12, D=64
//
// vs round 3 (passed, 584us, attn=443us @ 7% MfmaUtil / 24% occupancy):
//  - whole pipeline in f16 (11-bit mantissa): xq ints exact, W in normal range
//    (scale applied in GEMM epilogue, not folded -> no f16 subnormal weights).
//    Kills the hi/lo split (2-3x fewer MFMA) and halves all staging bytes.
//  - attention: 2-pass recompute (exact row max; ITA softmax is not online-
//    rescalable by non-integer shifts). Block=128 q-rows x 8 waves; K/V staged
//    to LDS via global_load_lds with pre-swizzled source (conflict-free reads),
//    double-buffered 2-phase. LDS 42KB (was 132KB). P transposed via 1.25KB
//    wave-private LDS. Grid bh-major for per-XCD K/V L2 locality.
//  - Q/K/V projections fused into ONE GEMM (Bt = 2304-col concat), 2-phase.

typedef unsigned short u16;
typedef __attribute__((ext_vector_type(8))) short short8;
typedef __attribute__((ext_vector_type(8))) _Float16 half8;
typedef __attribute__((ext_vector_type(4))) float f32x4;

#define LOG2E_F 1.4426950408889634f

static __device__ __forceinline__ half8 s2h(short8 s) {
  union { short8 s; half8 h; } u; u.s = s; return u.h;
}
static __device__ __forceinline__ f32x4 mfma16(short8 a, short8 b, f32x4 c) {
  return __builtin_amdgcn_mfma_f32_16x16x32_f16(s2h(a), s2h(b), c, 0, 0, 0);
}
static __device__ __forceinline__ u16 f2h(float f) {
  union { _Float16 h; u16 u; } v; v.h = (_Float16)f; return v.u;
}
static __device__ __forceinline__ void gload16(const void* g, void* l) {
  __builtin_amdgcn_global_load_lds(
      (const __attribute__((address_space(1))) void*)g,
      (__attribute__((address_space(3))) void*)l, 16, 0, 0);
}

// ---------------- amax reduction ----------------
__global__ __launch_bounds__(256) void amax_part_kernel(
    const float4* __restrict__ x, float* __restrict__ part, int n4) {
  float m = 0.f;
  int i = blockIdx.x * 256 + threadIdx.x;
  const int stride = gridDim.x * 256;
  for (; i < n4; i += stride) {
    float4 v = x[i];
    m = fmaxf(m, fmaxf(fmaxf(fabsf(v.x), fabsf(v.y)),
                       fmaxf(fabsf(v.z), fabsf(v.w))));
  }
  #pragma unroll
  for (int o = 1; o < 64; o <<= 1) m = fmaxf(m, __shfl_xor(m, o));
  __shared__ float sw[4];
  if ((threadIdx.x & 63) == 0) sw[threadIdx.x >> 6] = m;
  __syncthreads();
  if (threadIdx.x == 0)
    part[blockIdx.x] = fmaxf(fmaxf(sw[0], sw[1]), fmaxf(sw[2], sw[3]));
}

__global__ __launch_bounds__(256) void amax_fin_kernel(
    const float* __restrict__ part, double* __restrict__ dsc,
    float* __restrict__ dscf) {
  const int t = threadIdx.x;
  float m = fmaxf(fmaxf(part[t], part[t + 256]),
                  fmaxf(part[t + 512], part[t + 768]));
  #pragma unroll
  for (int o = 1; o < 64; o <<= 1) m = fmaxf(m, __shfl_xor(m, o));
  __shared__ float sw[4];
  if ((t & 63) == 0) sw[t >> 6] = m;
  __syncthreads();
  if (t == 0) {
    double sd = (double)(fmaxf(fmaxf(sw[0], sw[1]), fmaxf(sw[2], sw[3]))) / 127.0;
    if (sd < 1e-8) sd = 1e-8;
    dsc[0] = sd;
    dsc[1] = 1.0 / sd;
    dscf[0] = (float)sd;
  }
}

// ---------------- quantize: xq = clip(rint(x/s),-128,127), exact in f16 -----
__global__ __launch_bounds__(256) void quant_kernel(
    const float4* __restrict__ x, u16* __restrict__ xq,
    const double* __restrict__ dsc, int n4) {
  const double rinv = dsc[1];
  int i = blockIdx.x * 256 + threadIdx.x;
  const int stride = gridDim.x * 256;
  for (; i < n4; i += stride) {
    float4 v = x[i];
    ushort4 u;
    u.x = f2h((float)fmin(fmax(rint((double)v.x * rinv), -128.0), 127.0));
    u.y = f2h((float)fmin(fmax(rint((double)v.y * rinv), -128.0), 127.0));
    u.z = f2h((float)fmin(fmax(rint((double)v.z * rinv), -128.0), 127.0));
    u.w = f2h((float)fmin(fmax(rint((double)v.w * rinv), -128.0), 127.0));
    *(ushort4*)&xq[(size_t)i * 4] = u;
  }
}

// ---------------- weight prep: transpose to f16 (NO scale folded) -----------
// Wcat rows: [0,768)=Wq^T, [768,1536)=Wk^T, [1536,2304)=Wv^T. bcat = concat biases.
__global__ __launch_bounds__(256) void prep_weights_kernel(
    const float* __restrict__ Wq, const float* __restrict__ Wk,
    const float* __restrict__ Wv, const float* __restrict__ Wo,
    const float* __restrict__ bq, const float* __restrict__ bk,
    const float* __restrict__ bv,
    u16* __restrict__ Wcat, u16* __restrict__ Wot, float* __restrict__ bcat) {
  int idx = blockIdx.x * 256 + threadIdx.x;
  if (idx >= 768 * 768) return;
  const int n = idx / 768, k = idx - n * 768;
  const size_t src = (size_t)k * 768 + n;
  Wcat[idx] = f2h(Wq[src]);
  Wcat[idx + 768 * 768] = f2h(Wk[src]);
  Wcat[idx + 2 * 768 * 768] = f2h(Wv[src]);
  Wot[idx] = f2h(Wo[src]);
  if (idx < 768) {
    bcat[idx] = bq[idx];
    bcat[idx + 768] = bk[idx];
    bcat[idx + 1536] = bv[idx];
  }
}

// ---------------- GEMM (f16, 128x128 tile, 2-phase dbuf) --------------------
// C[m,n] = (sum_k A[m,k]*Bt[n,k]) * scale + bias[n]
// MODE 0: n in [0,2304): seg 0 -> Q [B,H,N,D], seg 1 -> K, seg 2 -> Vt [B,H,D,N]
// MODE 1: fp32 out [M,768]
template <int MODE>
__global__ __launch_bounds__(256) void gemm_f16(
    const u16* __restrict__ A, const u16* __restrict__ Bt,
    const float* __restrict__ bias, const float* __restrict__ scale_p,
    u16* __restrict__ Oq, u16* __restrict__ Ok, u16* __restrict__ Ovt,
    float* __restrict__ Of) {
  __shared__ u16 As[2][128 * 32];
  __shared__ u16 Bs[2][128 * 32];
  const int K = 768, nk = 24;
  const int tid = threadIdx.x;
  const int w = tid >> 6, l = tid & 63;
  const int l15 = l & 15, lk = l >> 4;
  const int wr = w >> 1, wc = w & 1;
  const int tn = blockIdx.x, tm = blockIdx.y;
  f32x4 acc[4][4] = {};
  const int rA = tid >> 2;
  const int c8 = (tid & 3) * 8;
  const u16* gA = A + (size_t)(tm * 128 + rA) * K + c8;
  const u16* gB = Bt + (size_t)(tn * 128 + rA) * K + c8;

  // prologue: stage tile 0 into buf 0
  {
    char* lA = (char*)As[0] + w * 1024;
    char* lB = (char*)Bs[0] + w * 1024;
    gload16(gA, lA);
    gload16(gA + (size_t)64 * K, lA + 4096);
    gload16(gB, lB);
    gload16(gB + (size_t)64 * K, lB + 4096);
  }
  __syncthreads();

  for (int kt = 0; kt < nk; ++kt) {
    const int buf = kt & 1;
    if (kt + 1 < nk) {  // issue next-tile stage before compute (2-phase)
      const int k0 = (kt + 1) * 32;
      char* lA = (char*)As[buf ^ 1] + w * 1024;
      char* lB = (char*)Bs[buf ^ 1] + w * 1024;
      gload16(gA + k0, lA);
      gload16(gA + k0 + (size_t)64 * K, lA + 4096);
      gload16(gB + k0, lB);
      gload16(gB + k0 + (size_t)64 * K, lB + 4096);
    }
    short8 af[4], bf[4];
    #pragma unroll
    for (int mi = 0; mi < 4; ++mi)
      af[mi] = *(const short8*)&As[buf][(wr * 64 + mi * 16 + l15) * 32 + lk * 8];
    #pragma unroll
    for (int ni = 0; ni < 4; ++ni)
      bf[ni] = *(const short8*)&Bs[buf][(wc * 64 + ni * 16 + l15) * 32 + lk * 8];
    #pragma unroll
    for (int mi = 0; mi < 4; ++mi)
      #pragma unroll
      for (int ni = 0; ni < 4; ++ni)
        acc[mi][ni] = mfma16(af[mi], bf[ni], acc[mi][ni]);
    __syncthreads();  // drains vmcnt (stage done) + lgkm, one barrier/tile
  }

  const float s = (MODE == 0) ? *scale_p : 1.0f;
  const int seg = (MODE == 0) ? (tn / 6) : 0;
  #pragma unroll
  for (int mi = 0; mi < 4; ++mi) {
    #pragma unroll
    for (int ni = 0; ni < 4; ++ni) {
      #pragma unroll
      for (int j = 0; j < 4; ++j) {
        const int gm = tm * 128 + wr * 64 + mi * 16 + lk * 4 + j;
        const int c = tn * 128 + wc * 64 + ni * 16 + l15;
        if (MODE == 0) {
          const int gc = c - seg * 768;
          const float v = acc[mi][ni][j] * s + bias[c];
          const int b = gm >> 10, n = gm & 1023, h = gc >> 6, d = gc & 63;
          if (seg == 0)
            Oq[(((size_t)b * 12 + h) * 1024 + n) * 64 + d] = f2h(v);
          else if (seg == 1)
            Ok[(((size_t)b * 12 + h) * 1024 + n) * 64 + d] = f2h(v);
          else
            Ovt[(((size_t)b * 12 + h) * 64 + d) * 1024 + n] = f2h(v);
        } else {
          Of[(size_t)gm * 768 + c] = acc[mi][ni][j] + bias[c];
        }
      }
    }
  }
}

// ---------------- fused attention (flash, 2-pass exact-max) -----------------
// grid (96 bh, 8 qt), 512 threads = 8 waves; wave w owns q-rows qt*128+w*16..+15.
// Pass A: exact row max of S over all 1024 keys (K staged in LDS, dbuf).
// Pass B: recompute S, ITA softmax p, PV accumulate (K+V staged, dbuf).
// K/V LDS tiles are XOR-swizzled via pre-swizzled global source (m173):
//   global chunk c of row r lives at LDS slot c^(r&7) -> conflict-free b128 reads.
__global__ __launch_bounds__(512, 4) void attn_kernel(
    const u16* __restrict__ Q, const u16* __restrict__ K,
    const u16* __restrict__ Vt, u16* __restrict__ ctx) {
  __shared__ u16 Ks[2][64 * 64];   // 16 KB
  __shared__ u16 Vs[2][64 * 64];   // 16 KB
  __shared__ u16 Pw[8][16 * 40];   // 10 KB, wave-private P transpose buffers
  const int bh = blockIdx.x, qt = blockIdx.y;
  const int b = bh / 12, h = bh - b * 12;
  const int tid = threadIdx.x;
  const int w = tid >> 6, l = tid & 63;
  const int l15 = l & 15, lk = l >> 4;
  const int xr = l15 & 7;

  // Q A-fragments (16 q-rows x 64 d), direct from global
  const size_t qoff = ((size_t)bh * 1024 + qt * 128 + w * 16 + l15) * 64 + lk * 8;
  const short8 qa0 = *(const short8*)(Q + qoff);
  const short8 qa1 = *(const short8*)(Q + qoff + 32);

  // staging: thread t covers tile row srow, pre-swizzled source chunk
  const int srow = w * 8 + (l >> 3);
  const int schunk = ((l & 7) ^ ((l >> 3) & 7)) * 8;
  const u16* Kg = K + ((size_t)bh * 1024 + srow) * 64 + schunk;
  const u16* Vg = Vt + ((size_t)bh * 64 + srow) * 1024 + schunk;
  u16* const ksd[2] = {&Ks[0][w * 512], &Ks[1][w * 512]};
  u16* const vsd[2] = {&Vs[0][w * 512], &Vs[1][w * 512]};

  // ---- pass A: exact row max ----
  f32x4 mx = {-3e38f, -3e38f, -3e38f, -3e38f};
  gload16(Kg, ksd[0]);
  __syncthreads();
  for (int kt = 0; kt < 16; ++kt) {
    const int buf = kt & 1;
    if (kt < 15) gload16(Kg + (size_t)(kt + 1) * 4096, ksd[buf ^ 1]);
    const u16* kb = Ks[buf];
    #pragma unroll
    for (int ks = 0; ks < 4; ++ks) {
      short8 k0 = *(const short8*)&kb[(ks * 16 + l15) * 64 + ((lk ^ xr) * 8)];
      short8 k1 = *(const short8*)&kb[(ks * 16 + l15) * 64 + (((lk + 4) ^ xr) * 8)];
      f32x4 sv = {0.f, 0.f, 0.f, 0.f};
      sv = mfma16(qa0, k0, sv);
      sv = mfma16(qa1, k1, sv);
      #pragma unroll
      for (int j = 0; j < 4; ++j) mx[j] = fmaxf(mx[j], sv[j]);
    }
    __syncthreads();
  }
  #pragma unroll
  for (int o = 1; o < 16; o <<= 1) {
    #pragma unroll
    for (int j = 0; j < 4; ++j) mx[j] = fmaxf(mx[j], __shfl_xor(mx[j], o));
  }
  f32x4 mz;
  #pragma unroll
  for (int j = 0; j < 4; ++j) mz[j] = mx[j] * LOG2E_F;  // = max(z), exact

  // ---- pass B: recompute S, softmax, PV ----
  f32x4 sum = {0.f, 0.f, 0.f, 0.f};
  f32x4 pv[4] = {};
  u16* const pw = Pw[w];
  gload16(Kg, ksd[0]);
  gload16(Vg, vsd[0]);
  __syncthreads();
  for (int kt = 0; kt < 16; ++kt) {
    const int buf = kt & 1;
    if (kt < 15) {
      gload16(Kg + (size_t)(kt + 1) * 4096, ksd[buf ^ 1]);
      gload16(Vg + (size_t)(kt + 1) * 64, vsd[buf ^ 1]);
    }
    const u16* kb = Ks[buf];
    const u16* vb = Vs[buf];
    #pragma unroll
    for (int ko = 0; ko < 2; ++ko) {
      #pragma unroll
      for (int ks2 = 0; ks2 < 2; ++ks2) {
        const int ks = ko * 2 + ks2;
        short8 k0 = *(const short8*)&kb[(ks * 16 + l15) * 64 + ((lk ^ xr) * 8)];
        short8 k1 = *(const short8*)&kb[(ks * 16 + l15) * 64 + (((lk + 4) ^ xr) * 8)];
        f32x4 sv = {0.f, 0.f, 0.f, 0.f};
        sv = mfma16(qa0, k0, sv);
        sv = mfma16(qa1, k1, sv);
        #pragma unroll
        for (int j = 0; j < 4; ++j) {
          float z = sv[j] * LOG2E_F;
          float zz = z - mz[j];
          float zi = floorf(zz);
          float p = ldexpf(1.0f + (zz - zi), (int)zi);  // exact 2^zi*(1+zf)
          sum[j] += p;
          pw[(lk * 4 + j) * 40 + ks2 * 16 + l15] = f2h(p);
        }
      }
      // make wave's Pw writes visible before cross-lane A-frag read
      asm volatile("s_waitcnt lgkmcnt(0)" ::: "memory");
      short8 pa = *(const short8*)&pw[l15 * 40 + lk * 8];
      #pragma unroll
      for (int dt = 0; dt < 4; ++dt) {
        short8 vv = *(const short8*)&vb[(dt * 16 + l15) * 64 +
                                        (((lk + 4 * ko) ^ xr) * 8)];
        pv[dt] = mfma16(pa, vv, pv[dt]);
      }
    }
    __syncthreads();
  }
  #pragma unroll
  for (int o = 1; o < 16; o <<= 1) {
    #pragma unroll
    for (int j = 0; j < 4; ++j) sum[j] += __shfl_xor(sum[j], o);
  }
  const int nrow = qt * 128 + w * 16 + lk * 4;
  #pragma unroll
  for (int dt = 0; dt < 4; ++dt) {
    #pragma unroll
    for (int j = 0; j < 4; ++j) {
      float v = pv[dt][j] / sum[j];
      ctx[((size_t)b * 1024 + nrow + j) * 768 + h * 64 + dt * 16 + l15] = f2h(v);
    }
  }
}

// ---------------- host ----------------
extern "C" void kernel_launch(void* const* d_in, const int* in_sizes, int n_in,
                              void* d_out, int out_size, void* d_ws, size_t ws_size,
                              hipStream_t stream) {
  const float* x  = (const float*)d_in[0];
  const float* Wq = (const float*)d_in[1];
  const float* bq = (const float*)d_in[2];
  const float* Wk = (const float*)d_in[3];
  const float* bk = (const float*)d_in[4];
  const float* Wv = (const float*)d_in[5];
  const float* bv = (const float*)d_in[6];
  const float* Wo = (const float*)d_in[7];
  const float* bo = (const float*)d_in[8];
  float* out = (float*)d_out;

  char* ws = (char*)d_ws;
  float* part  = (float*)ws;               // 1024 f32
  double* dsc  = (double*)(ws + 4096);     // {s, 1/s} f64
  float* dscf  = (float*)(ws + 4112);      // s f32
  float* bcat  = (float*)(ws + 8192);      // 2304 f32
  size_t off = 8192 + 16384;
  const size_t WB = (size_t)768 * 768;
  const size_t XB = (size_t)8192 * 768;
  u16* xq   = (u16*)(ws + off); off += XB * 2;
  u16* Wcat = (u16*)(ws + off); off += 3 * WB * 2;
  u16* Wot  = (u16*)(ws + off); off += WB * 2;
  u16* Qb   = (u16*)(ws + off); off += XB * 2;
  u16* Kb   = (u16*)(ws + off); off += XB * 2;
  u16* Vtb  = (u16*)(ws + off); off += XB * 2;
  u16* ctx  = xq;  // xq dead after gemm_f16<0>; attn runs after -> safe alias
  (void)ws_size; (void)in_sizes; (void)n_in; (void)out_size;

  const int n4 = (8 * 1024 * 768) / 4;
  amax_part_kernel<<<1024, 256, 0, stream>>>((const float4*)x, part, n4);
  amax_fin_kernel<<<1, 256, 0, stream>>>(part, dsc, dscf);
  quant_kernel<<<2048, 256, 0, stream>>>((const float4*)x, xq, dsc, n4);
  prep_weights_kernel<<<2304, 256, 0, stream>>>(Wq, Wk, Wv, Wo, bq, bk, bv,
                                                Wcat, Wot, bcat);
  gemm_f16<0><<<dim3(18, 64), 256, 0, stream>>>(xq, Wcat, bcat, dscf,
                                                Qb, Kb, Vtb, nullptr);
  attn_kernel<<<dim3(96, 8), 512, 0, stream>>>(Qb, Kb, Vtb, ctx);
  gemm_f16<1><<<dim3(6, 64), 256, 0, stream>>>(ctx, Wot, bo, nullptr,
                                               nullptr, nullptr, nullptr, out);
}